// Round 2
// baseline (571.403 us; speedup 1.0000x reference)
//
#include <hip/hip_runtime.h>

// out[b, m, p, q] = (1/SIDE^2) * sum_k vert[p,k] * hor[q,k]
//   m=0 (hf): K=64, x = {a0, b1-STRIP}, y = {b0, a1}
//   m=1 (ri): K=32, x = a0, y = b0
// hor/vert normalized by 1/SIDE (absorbs /PIXEL_AREA, keeps values in [0,1] for bf16).
//
// Round-2 experiment: full-row slab blocks + fill-like stores.
//  Block = 32 p-rows x 512 q  ==> each block's output is one CONTIGUOUS 64 KiB
//  region. Epilogue goes acc -> padded f32 LDS tile -> linear global stores
//  (64 lanes x 16 B = 1 KB contiguous per instruction, sequential per block),
//  matching the 6.2 TB/s fill's access pattern. Stores issue once at block end
//  -> s_endpgm with stores in flight -> background drain overlaps next block's
//  prologue (the round-0 pipeline, which round-1's in-block loop broke via
//  acc-VGPR-reuse vmcnt hazards).

#define P_DIM 512
#define SLAB  32          // p-rows per block
#define H_ROWS 512        // q-rows staged (full width)
#define H_STRIDE 72       // 64 + 8 pad shorts: b128 frag reads conflict-free-ish
#define V_STRIDE 72
#define EPI_STRIDE 516    // f32 epilogue tile row stride: 516 mod 32 banks = 4 -> even spread

#define H_BYTES (H_ROWS * H_STRIDE * 2)   // 73728
#define V_BYTES (SLAB * V_STRIDE * 2)     // 4608

constexpr float SIDEF     = (float)(1.5707963267948966 / 512.0);
constexpr float STRIPF    = (float)(1.5707963267948966);
constexpr float INV_SIDEF = (float)(512.0 / 1.5707963267948966);

typedef __attribute__((ext_vector_type(8))) short bf16x8;
typedef __attribute__((ext_vector_type(4))) float f32x4;

__device__ __forceinline__ unsigned short f2bf(float f) {
    unsigned int u = __float_as_uint(f);
    u += 0x7fffu + ((u >> 16) & 1u);   // round-to-nearest-even
    return (unsigned short)(u >> 16);
}

__global__ __launch_bounds__(256, 2)
void raster_kernel(const float* __restrict__ iv00, const float* __restrict__ iv01,
                   float* __restrict__ out)
{
    const int b  = blockIdx.z;
    const int m  = blockIdx.y;
    const int tp = blockIdx.x * SLAB;   // p-slab origin

    __shared__ __align__(16) unsigned char smem[H_BYTES + V_BYTES + 512];
    unsigned short* h_s = (unsigned short*)smem;             // [512][72] bf16 hor
    unsigned short* v_s = (unsigned short*)(smem + H_BYTES); // [32][72]  bf16 vert
    float* xk = (float*)(smem + H_BYTES + V_BYTES);          // [64]
    float* yk = xk + 64;
    float* epi = (float*)smem;  // [SLAB][EPI_STRIDE] f32 — reuses h_s area after MFMA

    const int tid = threadIdx.x;

    // Batch interval endpoints (once per block).
    if (tid < 32) {
        float a0 = iv00[b * 64 + 2 * tid];
        float b0 = iv00[b * 64 + 2 * tid + 1];
        if (m == 0) {
            float a1 = iv01[b * 64 + 2 * tid];
            float b1 = iv01[b * 64 + 2 * tid + 1];
            xk[tid]      = a0;            yk[tid]      = b0;
            xk[tid + 32] = b1 - STRIPF;   yk[tid + 32] = a1;
        } else {
            xk[tid] = a0;  yk[tid] = b0;
        }
    }
    __syncthreads();

    // Per-thread fixed k (256 % K == 0); hoist k-dependent terms.
    const int kbits = (m == 0) ? 6 : 5;
    const int K     = 1 << kbits;
    const int k     = tid & (K - 1);
    const int r0    = tid >> kbits;
    const int rstep = 256 >> kbits;
    const float xv = xk[k], yv = yk[k];
    const float h_t1 = SIDEF - xv;            // h = min(SIDE, q0 + h_t1, yv - q0)
    const float v_t1 = SIDEF - yv;            // v = min(SIDE, py + v_t1, xv + STRIP - py)
    const float v_t2 = xv + STRIPF;

    // Stage vert tile: 32 p-rows of this slab.
    for (int r = r0; r < SLAB; r += rstep) {
        float py = (float)(511 - (tp + r)) * SIDEF;  // PY[p]
        float v = (m == 0) ? fminf(SIDEF, fminf(py + v_t1, v_t2 - py))
                           : fminf(SIDEF, yv - py);
        v_s[r * V_STRIDE + k] = f2bf(fmaxf(v, 0.0f) * INV_SIDEF);
    }
    // Stage hor tile: ALL 512 q-rows.
    for (int r = r0; r < H_ROWS; r += rstep) {
        float q0 = (float)r * SIDEF;                 // PX[q]
        float h = (m == 0) ? fminf(SIDEF, fminf(q0 + h_t1, yv - q0))
                           : fminf(SIDEF, q0 + h_t1);
        h_s[r * H_STRIDE + k] = f2bf(fmaxf(h, 0.0f) * INV_SIDEF);
    }
    __syncthreads();

    const int lane = tid & 63;
    const int wave = tid >> 6;     // wave owns q-range [wave*128, wave*128+128)
    const int col  = lane & 15;    // A row (q) / B row (p) / D col (p)
    const int quad = lane >> 4;    // k-chunk select; D row group (q)
    const int nks  = (m == 0) ? 2 : 1;

    f32x4 acc[8][2];               // [q-subtile][p-subtile]
    #pragma unroll
    for (int qs = 0; qs < 8; ++qs)
        #pragma unroll
        for (int ps = 0; ps < 2; ++ps)
            acc[qs][ps] = (f32x4){0.f, 0.f, 0.f, 0.f};

    for (int ks = 0; ks < nks; ++ks) {
        const int k0 = ks * 32 + quad * 8;
        bf16x8 b0 = *(const bf16x8*)&v_s[(     col) * V_STRIDE + k0];
        bf16x8 b1 = *(const bf16x8*)&v_s[(16 + col) * V_STRIDE + k0];
        #pragma unroll
        for (int qs = 0; qs < 8; ++qs) {
            bf16x8 a = *(const bf16x8*)&h_s[(wave * 128 + qs * 16 + col) * H_STRIDE + k0];
            acc[qs][0] = __builtin_amdgcn_mfma_f32_16x16x32_bf16(a, b0, acc[qs][0], 0, 0, 0);
            acc[qs][1] = __builtin_amdgcn_mfma_f32_16x16x32_bf16(a, b1, acc[qs][1], 0, 0, 0);
        }
    }
    __syncthreads();   // all waves done reading h_s -> safe to overwrite with epi tile

    // acc -> f32 LDS tile [SLAB][EPI_STRIDE].
    // D mapping: q = wave*128 + qs*16 + quad*4 + reg, p_local = ps*16 + col.
    // Bank check per instr: (516*col + 4*quad) mod 32 spreads 64 lanes evenly
    // over all 32 banks (8 lanes per 4-bank group) -> minimum 8 phases, no excess.
    #pragma unroll
    for (int qs = 0; qs < 8; ++qs) {
        #pragma unroll
        for (int ps = 0; ps < 2; ++ps) {
            int p_loc = ps * 16 + col;
            int q     = wave * 128 + qs * 16 + quad * 4;
            *(f32x4*)&epi[p_loc * EPI_STRIDE + q] = acc[qs][ps];
        }
    }
    __syncthreads();

    // Linear copy: slab = 32 full rows = contiguous 64 KiB at oslab.
    // 64 lanes x 16 B = 1 KB contiguous per instruction, sequential over i.
    float* oslab = out + (size_t)(b * 2 + m) * P_DIM * P_DIM + (size_t)tp * P_DIM;
    #pragma unroll
    for (int i = 0; i < 16; ++i) {
        int fi  = i * 1024 + tid * 4;      // linear float index in the 64 KiB slab
        int row = fi >> 9;                 // /512
        int q   = fi & 511;
        *(f32x4*)&oslab[fi] = *(const f32x4*)&epi[row * EPI_STRIDE + q];
    }
}

extern "C" void kernel_launch(void* const* d_in, const int* in_sizes, int n_in,
                              void* d_out, int out_size, void* d_ws, size_t ws_size,
                              hipStream_t stream) {
    const float* iv00 = (const float*)d_in[0];
    const float* iv01 = (const float*)d_in[1];
    float* out = (float*)d_out;
    dim3 grid(P_DIM / SLAB, 2, 256);   // 16 p-slabs x 2 matrices x 256 batches
    raster_kernel<<<grid, dim3(256), 0, stream>>>(iv00, iv01, out);
}